// Round 7
// baseline (414.173 us; speedup 1.0000x reference)
//
#include <hip/hip_runtime.h>
#include <stdint.h>

// Binarized 5-layer MLP, B=32768, dims 784->256->256->256->256->10.
// Round 17: occupancy experiment, take 3.
// r16 evidence: profile shows LDS=12800 => the <512,64> fallback ran; the
// occupancy gate (>=5 blocks/CU) REJECTED the <1024,32> variant. Cause:
// launch_bounds(256,4) hands the allocator a 128-VGPR budget, it uses it,
// capacity == exactly 4/CU == r15's zero-margin deadlock. Fix: compile the
// 1024 variant with launch_bounds(256,6) -> VGPR cap 85 -> capacity >=6/CU
// (32-row variant needs ~60 regs; 64-row needed 68). Gate unchanged (>=5).
// Everything else byte-identical to r16's proven structure:
//   regular launch + zero-cache-op hierarchical barrier (r14: 433->131us),
//   all cross-block data read-only or MALL atomics, relaxed-poll gen lines.
// Current bottleneck model (r14/r16 counters): fused = 131us @ 2 blocks/CU,
// VALUBusy 27% (~35us real VALU), FETCH 52MB @ 460GB/s (latency- not
// BW-bound) => ~90us latency stall at 8 waves/CU. Doubling resident waves
// should roughly halve the stall.
// Math (verified r12-r16, absmax 0.00195): d = popcount(a XOR w);
// binarize(BN(h)) == (A*d + C >= 0), A = -2*g*s, C = 2*g*s*mean_d + b,
// s = rsqrt(4*(E[d^2]-E[d]^2)+eps). Stats = exact integer sums in 16
// replicated atomic slots; consumers reduce replicas.

typedef unsigned long long u64;

#define NREP 16

// ---- workspace layout (bytes) ----
#define OFF_WB0   0u          // u64 [16][256] = 32768 (words 0..12 used)
#define OFF_WB1   32768u      // u64 [4][256] = 8192
#define OFF_WB2   40960u
#define OFF_WB3   49152u
#define OFF_WB4   57344u      // u64 [4][16] = 512 (10 cols used)
#define OFF_SUMD  57856u      // int32 [16][5][256] = 81920
#define OFF_SUMDD 139776u     // u64   [16][5][256] = 163840
#define OFF_BAR   303616u     // 81 lines x 256B: <=64 group cnts, 1 root, 16 gen
#define ZERO_INT4 16656       // (81920+163840+81*256)/16, zeroed from OFF_SUMD

// 784-elem row -> 13 packed u64 words (consistent permuted bit order).
__device__ __forceinline__ u64 pack784_sel(const float* __restrict__ src,
                                           float thr, int lane) {
  u64 w[13];
  const float4* s4 = (const float4*)src;
#pragma unroll
  for (int j = 0; j < 3; ++j) {
    float4 v = s4[j * 64 + lane];
    w[4*j+0] = __ballot(v.x >= thr);
    w[4*j+1] = __ballot(v.y >= thr);
    w[4*j+2] = __ballot(v.z >= thr);
    w[4*j+3] = __ballot(v.w >= thr);
  }
  float4 v = make_float4(-1.f, -1.f, -1.f, -1.f);
  if (lane < 4) v = s4[192 + lane];
  u64 m0 = __ballot(v.x >= thr) & 0xFull;
  u64 m1 = __ballot(v.y >= thr) & 0xFull;
  u64 m2 = __ballot(v.z >= thr) & 0xFull;
  u64 m3 = __ballot(v.w >= thr) & 0xFull;
  w[12] = m0 | (m1 << 4) | (m2 << 8) | (m3 << 12);
  u64 sel = 0;
#pragma unroll
  for (int i = 0; i < 13; ++i) sel = (lane == i) ? w[i] : sel;
  return sel;
}

// 256-elem row -> 4 packed u64 words; bit l of word j <-> element 64*j+l.
__device__ __forceinline__ u64 pack256_sel(const float* __restrict__ src, int lane) {
  u64 w[4];
#pragma unroll
  for (int j = 0; j < 4; ++j) w[j] = __ballot(src[j * 64 + lane] >= 0.0f);
  u64 sel = 0;
#pragma unroll
  for (int i = 0; i < 4; ++i) sel = (lane == i) ? w[i] : sel;
  return sel;
}

// Reduce the 16 stats replicas for (layer, col) via MALL-fresh atomic loads.
__device__ __forceinline__ void bn_gs_md(const int* __restrict__ sumd_rep,
                                         const u64* __restrict__ sumdd_rep,
                                         int layer, int col,
                                         const float* __restrict__ g,
                                         float& gs, float& md_out) {
  long long sd = 0; u64 sdd = 0;
#pragma unroll
  for (int r = 0; r < NREP; ++r) {
    sd  += __hip_atomic_load(&sumd_rep [(r * 5 + layer) * 256 + col],
                             __ATOMIC_RELAXED, __HIP_MEMORY_SCOPE_AGENT);
    sdd += __hip_atomic_load(&sumdd_rep[(r * 5 + layer) * 256 + col],
                             __ATOMIC_RELAXED, __HIP_MEMORY_SCOPE_AGENT);
  }
  double md  = (double)sd  * (1.0 / 32768.0);
  double mdd = (double)sdd * (1.0 / 32768.0);
  float var = (float)(4.0 * (mdd - md * md));
  float s   = rsqrtf(var + 1e-5f);
  gs = g[col] * s;
  md_out = (float)md;
}

#define DPK_SET(r, d) do { if ((r) & 1) dpk[(r) >> 1] |= ((unsigned)(d)) << 16; \
                           else dpk[(r) >> 1] = (unsigned)(d); } while (0)
#define DPK_GET(r) ((int)((dpk[(r) >> 1] >> (((r) & 1) * 16)) & 0xFFFFu))

// Stats add: returning atomic form so vmcnt-retire == completed at the MALL.
__device__ __forceinline__ void stats_add(int* pd, u64* pdd, int sd, u64 sdd) {
  int o1 = atomicAdd(pd, sd);
  u64 o2 = atomicAdd(pdd, sdd);
  asm volatile("" :: "v"(o1), "v"(o2));
}

// ---- zero-cache-op hierarchical grid barrier ----
// Monotonic counters; phase = 1..5. Lines 256B apart:
//   bar[g*64]            g<NGRP : group arrival counters
//   bar[NGRP*64]                : root counter
//   bar[(NGRP+1+r)*64]   r<16   : generation replicas
// __syncthreads() drains each wave's vmcnt before tid0 publishes arrival;
// polling is RELAXED on a replica line; consumers re-read stats at the MALL.
template<int NBLK>
__device__ __forceinline__ void grid_barrier(unsigned* bar, unsigned phase, int b) {
  constexpr unsigned NGRP = NBLK / 16;
  __syncthreads();
  if (threadIdx.x == 0) {
    asm volatile("s_waitcnt vmcnt(0)" ::: "memory");
    const unsigned g = (unsigned)b >> 4;           // b / 16
    unsigned a = __hip_atomic_fetch_add(&bar[g * 64], 1u, __ATOMIC_RELAXED,
                                        __HIP_MEMORY_SCOPE_AGENT) + 1u;
    bool released = false;
    if (a == phase * 16u) {                        // last of my group, this phase
      unsigned r = __hip_atomic_fetch_add(&bar[NGRP * 64], 1u, __ATOMIC_RELAXED,
                                          __HIP_MEMORY_SCOPE_AGENT) + 1u;
      if (r == phase * NGRP) {                     // last overall: release
#pragma unroll
        for (int i = 0; i < 16; ++i)
          __hip_atomic_store(&bar[(NGRP + 1 + i) * 64], phase, __ATOMIC_RELAXED,
                             __HIP_MEMORY_SCOPE_AGENT);
        released = true;
      }
    }
    if (!released) {
      const unsigned* genp = &bar[(NGRP + 1 + (b & 15)) * 64];
      while (__hip_atomic_load(genp, __ATOMIC_RELAXED,
                               __HIP_MEMORY_SCOPE_AGENT) < phase)
        __builtin_amdgcn_s_sleep(8);
    }
  }
  __syncthreads();
}

// ================= prep: pack weights + zero stats & barrier =================
__global__ __launch_bounds__(256) void pack_weights(
    const float* __restrict__ W0, const float* __restrict__ W1,
    const float* __restrict__ W2, const float* __restrict__ W3,
    const float* __restrict__ W4,
    u64* __restrict__ wb0, u64* __restrict__ wb1, u64* __restrict__ wb2,
    u64* __restrict__ wb3, u64* __restrict__ wb4, int4* __restrict__ zeroRgn) {
  const int b = blockIdx.x, tid = threadIdx.x;
  const int lane = tid & 63, wave = tid >> 6;
  int gid = b * 256 + tid;
  if (gid < ZERO_INT4) zeroRgn[gid] = make_int4(0, 0, 0, 0);
  if (b < 64) {
    int row = b * 4 + wave;
    u64 sel = pack784_sel(W0 + (size_t)row * 784, 0.0f, lane);
    if (lane < 13) wb0[lane * 256 + row] = sel;
  } else if (b < 128) {
    int row = (b - 64) * 4 + wave;
    u64 sel = pack256_sel(W1 + (size_t)row * 256, lane);
    if (lane < 4) wb1[lane * 256 + row] = sel;
  } else if (b < 192) {
    int row = (b - 128) * 4 + wave;
    u64 sel = pack256_sel(W2 + (size_t)row * 256, lane);
    if (lane < 4) wb2[lane * 256 + row] = sel;
  } else if (b < 256) {
    int row = (b - 192) * 4 + wave;
    u64 sel = pack256_sel(W3 + (size_t)row * 256, lane);
    if (lane < 4) wb3[lane * 256 + row] = sel;
  } else {
    for (int row = wave; row < 10; row += 4) {
      u64 sel = pack256_sel(W4 + (size_t)row * 256, lane);
      if (lane < 4) wb4[lane * 16 + row] = sel;
    }
  }
}

// ================= fused persistent kernel (regular launch) =================
// NBLK x RWS rows; NBLK*RWS == 32768.
// <1024,32>: launch_bounds(256,6) -> VGPR cap 85 -> capacity >=6 blocks/CU,
//            needs 4 -> margin. <512,64>: (256,3) (proven 68 VGPR, cap ~7).
template<int NBLK, int RWS>
__global__ __launch_bounds__(256, (NBLK >= 1024) ? 6 : 3) void fused_bnn(
    const float* __restrict__ x,
    const float* __restrict__ g0, const float* __restrict__ g1,
    const float* __restrict__ g2, const float* __restrict__ g3,
    const float* __restrict__ g4,
    const float* __restrict__ bb0, const float* __restrict__ bb1,
    const float* __restrict__ bb2, const float* __restrict__ bb3,
    const float* __restrict__ bb4,
    float* __restrict__ out, char* __restrict__ ws) {
  u64* wb0 = (u64*)(ws + OFF_WB0);
  u64* wb1 = (u64*)(ws + OFF_WB1);
  u64* wb2 = (u64*)(ws + OFF_WB2);
  u64* wb3 = (u64*)(ws + OFF_WB3);
  u64* wb4 = (u64*)(ws + OFF_WB4);
  int* sumd  = (int*)(ws + OFF_SUMD);
  u64* sumdd = (u64*)(ws + OFF_SUMDD);
  unsigned* bar = (unsigned*)(ws + OFF_BAR);

  const int b = blockIdx.x, tid = threadIdx.x;
  const int lane = tid & 63, wave = tid >> 6;
  const int row0 = b * RWS;           // this block owns rows row0..row0+RWS-1
  const int rep = b & (NREP - 1);
  constexpr int RPW = RWS / 4;        // rows packed per wave in P1

  __shared__ u64 aw[RWS * 16];        // layer-0 packed rows (13/16 words used)
  __shared__ u64 bits[RWS * 4];       // current activation bits
  __shared__ float sY[RWS * 10];      // layer-4 pre-softmax

  unsigned dpk[RWS / 2];              // RWS d-values, 2x16b packed, registers

  // ---- P1: layer 0 — pack RWS x-rows into LDS, d0 -> dpk, stats0
  {
    u64 w0  = wb0[ 0 * 256 + tid], w1  = wb0[ 1 * 256 + tid];
    u64 w2  = wb0[ 2 * 256 + tid], w3  = wb0[ 3 * 256 + tid];
    u64 w4  = wb0[ 4 * 256 + tid], w5  = wb0[ 5 * 256 + tid];
    u64 w6  = wb0[ 6 * 256 + tid], w7  = wb0[ 7 * 256 + tid];
    u64 w8  = wb0[ 8 * 256 + tid], w9  = wb0[ 9 * 256 + tid];
    u64 w10 = wb0[10 * 256 + tid], w11 = wb0[11 * 256 + tid];
    u64 w12 = wb0[12 * 256 + tid];
    const float* base = x + (size_t)(row0 + wave * RPW) * 784;
#pragma unroll 2
    for (int it = 0; it < RPW; ++it) {
      u64 sel = pack784_sel(base + (size_t)it * 784, 0.5f, lane);
      if (lane < 13) aw[(wave * RPW + it) * 16 + lane] = sel;  // words 13..15 never read
    }
    __syncthreads();
    int sd = 0; unsigned sdd = 0;   // RWS*784^2 <= 39.3M fits u32
#pragma unroll
    for (int r = 0; r < RWS; ++r) {
      const u64* ap = &aw[r * 16];
      int d = __popcll(ap[0] ^ w0)   + __popcll(ap[1] ^ w1)
            + __popcll(ap[2] ^ w2)   + __popcll(ap[3] ^ w3)
            + __popcll(ap[4] ^ w4)   + __popcll(ap[5] ^ w5)
            + __popcll(ap[6] ^ w6)   + __popcll(ap[7] ^ w7)
            + __popcll(ap[8] ^ w8)   + __popcll(ap[9] ^ w9)
            + __popcll(ap[10] ^ w10) + __popcll(ap[11] ^ w11)
            + __popcll(ap[12] ^ w12);
      DPK_SET(r, d);
      sd += d; sdd += (unsigned)(d * d);
    }
    stats_add(&sumd[(rep * 5 + 0) * 256 + tid],
              &sumdd[(rep * 5 + 0) * 256 + tid], sd, (u64)sdd);
  }
  grid_barrier<NBLK>(bar, 1, b);

  // ---- P2..P4: layers 1..3 — binarize dpk -> bits -> new dpk + next stats
#pragma unroll
  for (int k = 0; k < 3; ++k) {
    const float* gk  = (k == 0) ? g0  : (k == 1) ? g1  : g2;
    const float* bk  = (k == 0) ? bb0 : (k == 1) ? bb1 : bb2;
    const u64*   wbN = (k == 0) ? wb1 : (k == 1) ? wb2 : wb3;
    float gs, md;
    bn_gs_md(sumd, sumdd, k, tid, gk, gs, md);
    const float A = -2.0f * gs;
    const float C = fmaf(gs, 2.0f * md, bk[tid]);
#pragma unroll
    for (int r = 0; r < RWS; ++r) {
      bool bit = fmaf(A, (float)DPK_GET(r), C) >= 0.0f;
      u64 m = __ballot(bit);
      if (lane == 0) bits[r * 4 + wave] = m;
    }
    __syncthreads();
    u64 wn0 = wbN[0 * 256 + tid], wn1 = wbN[1 * 256 + tid];
    u64 wn2 = wbN[2 * 256 + tid], wn3 = wbN[3 * 256 + tid];
    int sd = 0; unsigned sdd = 0;   // RWS * 256^2 <= 4.2M fits u32
#pragma unroll
    for (int r = 0; r < RWS; ++r) {
      int d = __popcll(bits[r*4+0] ^ wn0) + __popcll(bits[r*4+1] ^ wn1)
            + __popcll(bits[r*4+2] ^ wn2) + __popcll(bits[r*4+3] ^ wn3);
      DPK_SET(r, d);
      sd += d; sdd += (unsigned)(d * d);
    }
    stats_add(&sumd[(rep * 5 + k + 1) * 256 + tid],
              &sumdd[(rep * 5 + k + 1) * 256 + tid], sd, (u64)sdd);
    grid_barrier<NBLK>(bar, 2 + k, b);
  }

  // ---- P5: layer 4 — binarize d3 -> bits -> d4 (10 cols, in dpk of tid<10)
  {
    float gs, md;
    bn_gs_md(sumd, sumdd, 3, tid, g3, gs, md);
    const float A = -2.0f * gs;
    const float C = fmaf(gs, 2.0f * md, bb3[tid]);
#pragma unroll
    for (int r = 0; r < RWS; ++r) {
      bool bit = fmaf(A, (float)DPK_GET(r), C) >= 0.0f;
      u64 m = __ballot(bit);
      if (lane == 0) bits[r * 4 + wave] = m;
    }
    __syncthreads();
    if (tid < 10) {
      u64 wn0 = wb4[0 * 16 + tid], wn1 = wb4[1 * 16 + tid];
      u64 wn2 = wb4[2 * 16 + tid], wn3 = wb4[3 * 16 + tid];
      int sd = 0; unsigned sdd = 0;
#pragma unroll
      for (int r = 0; r < RWS; ++r) {
        int d = __popcll(bits[r*4+0] ^ wn0) + __popcll(bits[r*4+1] ^ wn1)
              + __popcll(bits[r*4+2] ^ wn2) + __popcll(bits[r*4+3] ^ wn3);
        DPK_SET(r, d);
        sd += d; sdd += (unsigned)(d * d);
      }
      stats_add(&sumd[(rep * 5 + 4) * 256 + tid],
                &sumdd[(rep * 5 + 4) * 256 + tid], sd, (u64)sdd);
    }
  }
  grid_barrier<NBLK>(bar, 5, b);

  // ---- P6: BN4 + softmax + store
  {
    if (tid < 10) {
      float gs, md;
      bn_gs_md(sumd, sumdd, 4, tid, g4, gs, md);
      const float A = -2.0f * gs;
      const float C = fmaf(gs, 2.0f * md, bb4[tid]);
#pragma unroll
      for (int r = 0; r < RWS; ++r)
        sY[r * 10 + tid] = fmaf(A, (float)DPK_GET(r), C);
    }
    __syncthreads();
    if (tid < RWS) {
      float y[10]; float mx = -1e30f;
#pragma unroll
      for (int c = 0; c < 10; ++c) { y[c] = sY[tid * 10 + c]; mx = fmaxf(mx, y[c]); }
      float sum = 0.0f;
#pragma unroll
      for (int c = 0; c < 10; ++c) { y[c] = __expf(y[c] - mx); sum += y[c]; }
      float inv = 1.0f / sum;
      float* op = out + (size_t)(row0 + tid) * 10;
#pragma unroll
      for (int c = 0; c < 10; ++c) op[c] = y[c] * inv;
    }
  }
}

// ---------------- host ----------------
extern "C" void kernel_launch(void* const* d_in, const int* in_sizes, int n_in,
                              void* d_out, int out_size, void* d_ws, size_t ws_size,
                              hipStream_t stream) {
  (void)in_sizes; (void)n_in; (void)out_size; (void)ws_size;
  const float* x   = (const float*)d_in[0];
  const float* W0  = (const float*)d_in[1];
  const float* g0  = (const float*)d_in[2];
  const float* bb0 = (const float*)d_in[3];
  const float* W1  = (const float*)d_in[4];
  const float* g1  = (const float*)d_in[5];
  const float* bb1 = (const float*)d_in[6];
  const float* W2  = (const float*)d_in[7];
  const float* g2  = (const float*)d_in[8];
  const float* bb2 = (const float*)d_in[9];
  const float* W3  = (const float*)d_in[10];
  const float* g3  = (const float*)d_in[11];
  const float* bb3 = (const float*)d_in[12];
  const float* W4  = (const float*)d_in[13];
  const float* g4  = (const float*)d_in[14];
  const float* bb4 = (const float*)d_in[15];
  char* ws = (char*)d_ws;

  u64* wb0 = (u64*)(ws + OFF_WB0);
  u64* wb1 = (u64*)(ws + OFF_WB1);
  u64* wb2 = (u64*)(ws + OFF_WB2);
  u64* wb3 = (u64*)(ws + OFF_WB3);
  u64* wb4 = (u64*)(ws + OFF_WB4);

  pack_weights<<<257, 256, 0, stream>>>(W0, W1, W2, W3, W4,
                                        wb0, wb1, wb2, wb3, wb4,
                                        (int4*)(ws + OFF_SUMD));

  // One-time host-side occupancy check for the 1024-block variant.
  // Spin-barrier rule: only launch with VERIFIED margin (>=5 blocks/CU for a
  // 4/CU requirement). Otherwise the proven 512x64 geometry (needs 2/CU).
  static int cap1024 = -1;
  if (cap1024 < 0) {
    int nb = 0;
    const void* kptr = (const void*)fused_bnn<1024, 32>;
    if (hipOccupancyMaxActiveBlocksPerMultiprocessor(&nb, kptr, 256, 0)
        != hipSuccess) nb = 0;
    (void)hipGetLastError();
    cap1024 = nb;
  }

  if (cap1024 >= 5) {
    fused_bnn<1024, 32><<<1024, 256, 0, stream>>>(
        x, g0, g1, g2, g3, g4, bb0, bb1, bb2, bb3, bb4,
        (float*)d_out, ws);
  } else {
    fused_bnn<512, 64><<<512, 256, 0, stream>>>(
        x, g0, g1, g2, g3, g4, bb0, bb1, bb2, bb3, bb4,
        (float*)d_out, ws);
  }
}

// Round 8
// 267.419 us; speedup vs baseline: 1.5488x; 1.5488x over previous
//
#include <hip/hip_runtime.h>
#include <stdint.h>

// Binarized 5-layer MLP, B=32768, dims 784->256->256->256->256->10.
// Round 18: occupancy via WIDER BLOCKS, not VGPR caps.
// r17 evidence: 1024x32 @ launch_bounds(256,6) ran at 16 waves/CU but 199us
// (vs 131): VGPR 68->40 + WRITE +6.3MB = compiler sank the 13 weight words
// and spilled (r10's documented failure mode). Same VALU-issue time, worse
// schedule. Lesson: occupancy gains must preserve per-thread code quality.
// This round: fused2 = 512 blocks x 512 threads (8 waves), 64 rows/block;
// col = tid&255, half h = tid>>8, 32 rows/thread (dpk[16] -> FEWER regs than
// the proven 68-VGPR config). 2 blocks/CU = 16 waves/CU. Stats halves combine
// in LDS first => MALL same-address contention unchanged (32 RMWs). Mild
// launch_bounds(512,3) (cap 170, no spill pressure). Occupancy gate: need 2
// blocks/CU, require >=3; fallback = proven 131us 256-thread kernel.
// Barrier design unchanged (r14-verified): all cross-block data read-only or
// MALL atomics; hierarchical relaxed arrivals + relaxed poll; no cache ops.
// Math (verified r12-r17, absmax 0.00195): d = popcount(a XOR w);
// binarize(BN(h)) == (A*d + C >= 0), A = -2*g*s, C = 2*g*s*mean_d + b,
// s = rsqrt(4*(E[d^2]-E[d]^2)+eps). Stats = exact integer sums in 16
// replicated atomic slots; consumers reduce replicas.

typedef unsigned long long u64;

#define NREP 16

// ---- workspace layout (bytes) ----
#define OFF_WB0   0u          // u64 [16][256] = 32768 (words 0..12 used)
#define OFF_WB1   32768u      // u64 [4][256] = 8192
#define OFF_WB2   40960u
#define OFF_WB3   49152u
#define OFF_WB4   57344u      // u64 [4][16] = 512 (10 cols used)
#define OFF_SUMD  57856u      // int32 [16][5][256] = 81920
#define OFF_SUMDD 139776u     // u64   [16][5][256] = 163840
#define OFF_BAR   303616u     // 81 lines x 256B: <=64 group cnts, 1 root, 16 gen
#define ZERO_INT4 16656       // (81920+163840+81*256)/16, zeroed from OFF_SUMD

// 784-elem row -> 13 packed u64 words (consistent permuted bit order).
__device__ __forceinline__ u64 pack784_sel(const float* __restrict__ src,
                                           float thr, int lane) {
  u64 w[13];
  const float4* s4 = (const float4*)src;
#pragma unroll
  for (int j = 0; j < 3; ++j) {
    float4 v = s4[j * 64 + lane];
    w[4*j+0] = __ballot(v.x >= thr);
    w[4*j+1] = __ballot(v.y >= thr);
    w[4*j+2] = __ballot(v.z >= thr);
    w[4*j+3] = __ballot(v.w >= thr);
  }
  float4 v = make_float4(-1.f, -1.f, -1.f, -1.f);
  if (lane < 4) v = s4[192 + lane];
  u64 m0 = __ballot(v.x >= thr) & 0xFull;
  u64 m1 = __ballot(v.y >= thr) & 0xFull;
  u64 m2 = __ballot(v.z >= thr) & 0xFull;
  u64 m3 = __ballot(v.w >= thr) & 0xFull;
  w[12] = m0 | (m1 << 4) | (m2 << 8) | (m3 << 12);
  u64 sel = 0;
#pragma unroll
  for (int i = 0; i < 13; ++i) sel = (lane == i) ? w[i] : sel;
  return sel;
}

// 256-elem row -> 4 packed u64 words; bit l of word j <-> element 64*j+l.
__device__ __forceinline__ u64 pack256_sel(const float* __restrict__ src, int lane) {
  u64 w[4];
#pragma unroll
  for (int j = 0; j < 4; ++j) w[j] = __ballot(src[j * 64 + lane] >= 0.0f);
  u64 sel = 0;
#pragma unroll
  for (int i = 0; i < 4; ++i) sel = (lane == i) ? w[i] : sel;
  return sel;
}

// Reduce the 16 stats replicas for (layer, col) via MALL-fresh atomic loads.
__device__ __forceinline__ void bn_gs_md(const int* __restrict__ sumd_rep,
                                         const u64* __restrict__ sumdd_rep,
                                         int layer, int col,
                                         const float* __restrict__ g,
                                         float& gs, float& md_out) {
  long long sd = 0; u64 sdd = 0;
#pragma unroll
  for (int r = 0; r < NREP; ++r) {
    sd  += __hip_atomic_load(&sumd_rep [(r * 5 + layer) * 256 + col],
                             __ATOMIC_RELAXED, __HIP_MEMORY_SCOPE_AGENT);
    sdd += __hip_atomic_load(&sumdd_rep[(r * 5 + layer) * 256 + col],
                             __ATOMIC_RELAXED, __HIP_MEMORY_SCOPE_AGENT);
  }
  double md  = (double)sd  * (1.0 / 32768.0);
  double mdd = (double)sdd * (1.0 / 32768.0);
  float var = (float)(4.0 * (mdd - md * md));
  float s   = rsqrtf(var + 1e-5f);
  gs = g[col] * s;
  md_out = (float)md;
}

#define DPK_SET(r, d) do { if ((r) & 1) dpk[(r) >> 1] |= ((unsigned)(d)) << 16; \
                           else dpk[(r) >> 1] = (unsigned)(d); } while (0)
#define DPK_GET(r) ((int)((dpk[(r) >> 1] >> (((r) & 1) * 16)) & 0xFFFFu))

// Stats add: returning atomic form so vmcnt-retire == completed at the MALL.
__device__ __forceinline__ void stats_add(int* pd, u64* pdd, int sd, u64 sdd) {
  int o1 = atomicAdd(pd, sd);
  u64 o2 = atomicAdd(pdd, sdd);
  asm volatile("" :: "v"(o1), "v"(o2));
}

// ---- zero-cache-op hierarchical grid barrier (r14-verified) ----
template<int NBLK>
__device__ __forceinline__ void grid_barrier(unsigned* bar, unsigned phase, int b) {
  constexpr unsigned NGRP = NBLK / 16;
  __syncthreads();
  if (threadIdx.x == 0) {
    asm volatile("s_waitcnt vmcnt(0)" ::: "memory");
    const unsigned g = (unsigned)b >> 4;           // b / 16
    unsigned a = __hip_atomic_fetch_add(&bar[g * 64], 1u, __ATOMIC_RELAXED,
                                        __HIP_MEMORY_SCOPE_AGENT) + 1u;
    bool released = false;
    if (a == phase * 16u) {                        // last of my group, this phase
      unsigned r = __hip_atomic_fetch_add(&bar[NGRP * 64], 1u, __ATOMIC_RELAXED,
                                          __HIP_MEMORY_SCOPE_AGENT) + 1u;
      if (r == phase * NGRP) {                     // last overall: release
#pragma unroll
        for (int i = 0; i < 16; ++i)
          __hip_atomic_store(&bar[(NGRP + 1 + i) * 64], phase, __ATOMIC_RELAXED,
                             __HIP_MEMORY_SCOPE_AGENT);
        released = true;
      }
    }
    if (!released) {
      const unsigned* genp = &bar[(NGRP + 1 + (b & 15)) * 64];
      while (__hip_atomic_load(genp, __ATOMIC_RELAXED,
                               __HIP_MEMORY_SCOPE_AGENT) < phase)
        __builtin_amdgcn_s_sleep(8);
    }
  }
  __syncthreads();
}

// ================= prep: pack weights + zero stats & barrier =================
__global__ __launch_bounds__(256) void pack_weights(
    const float* __restrict__ W0, const float* __restrict__ W1,
    const float* __restrict__ W2, const float* __restrict__ W3,
    const float* __restrict__ W4,
    u64* __restrict__ wb0, u64* __restrict__ wb1, u64* __restrict__ wb2,
    u64* __restrict__ wb3, u64* __restrict__ wb4, int4* __restrict__ zeroRgn) {
  const int b = blockIdx.x, tid = threadIdx.x;
  const int lane = tid & 63, wave = tid >> 6;
  int gid = b * 256 + tid;
  if (gid < ZERO_INT4) zeroRgn[gid] = make_int4(0, 0, 0, 0);
  if (b < 64) {
    int row = b * 4 + wave;
    u64 sel = pack784_sel(W0 + (size_t)row * 784, 0.0f, lane);
    if (lane < 13) wb0[lane * 256 + row] = sel;
  } else if (b < 128) {
    int row = (b - 64) * 4 + wave;
    u64 sel = pack256_sel(W1 + (size_t)row * 256, lane);
    if (lane < 4) wb1[lane * 256 + row] = sel;
  } else if (b < 192) {
    int row = (b - 128) * 4 + wave;
    u64 sel = pack256_sel(W2 + (size_t)row * 256, lane);
    if (lane < 4) wb2[lane * 256 + row] = sel;
  } else if (b < 256) {
    int row = (b - 192) * 4 + wave;
    u64 sel = pack256_sel(W3 + (size_t)row * 256, lane);
    if (lane < 4) wb3[lane * 256 + row] = sel;
  } else {
    for (int row = wave; row < 10; row += 4) {
      u64 sel = pack256_sel(W4 + (size_t)row * 256, lane);
      if (lane < 4) wb4[lane * 16 + row] = sel;
    }
  }
}

// ================= fused2: 512 blocks x 512 threads, 64 rows/block =========
// col = tid&255, h = tid>>8; thread handles rows h*32..h*32+31 of its block.
// Waves 0-3 : h=0, col groups 0-3; waves 4-7: h=1.
__global__ __launch_bounds__(512, 3) void fused_bnn2(
    const float* __restrict__ x,
    const float* __restrict__ g0, const float* __restrict__ g1,
    const float* __restrict__ g2, const float* __restrict__ g3,
    const float* __restrict__ g4,
    const float* __restrict__ bb0, const float* __restrict__ bb1,
    const float* __restrict__ bb2, const float* __restrict__ bb3,
    const float* __restrict__ bb4,
    float* __restrict__ out, char* __restrict__ ws) {
  u64* wb0 = (u64*)(ws + OFF_WB0);
  u64* wb1 = (u64*)(ws + OFF_WB1);
  u64* wb2 = (u64*)(ws + OFF_WB2);
  u64* wb3 = (u64*)(ws + OFF_WB3);
  u64* wb4 = (u64*)(ws + OFF_WB4);
  int* sumd  = (int*)(ws + OFF_SUMD);
  u64* sumdd = (u64*)(ws + OFF_SUMDD);
  unsigned* bar = (unsigned*)(ws + OFF_BAR);

  const int b = blockIdx.x, tid = threadIdx.x;
  const int lane = tid & 63, wave = tid >> 6;   // wave 0..7
  const int col = tid & 255, h = tid >> 8;      // h in {0,1}
  const int cg = wave & 3, hw = wave >> 2;      // wave's col-group / half
  const int row0 = b * 64;
  const int rep = b & (NREP - 1);

  __shared__ u64 aw[64 * 16];       // 8 KB: layer-0 packed rows (13/16 used)
  __shared__ u64 bits[64 * 4];      // 2 KB: current activation bits
  __shared__ float sY[64 * 10];     // 2.5 KB: layer-4 pre-softmax
  __shared__ unsigned sdL[256];     // 1 KB: h=1 partial sum(d)
  __shared__ unsigned sddL[256];    // 1 KB: h=1 partial sum(d^2)

  unsigned dpk[16];                 // 32 d-values (this thread's half), 2x16b

  // ---- P1: layer 0 — pack 64 x-rows into LDS, d0 -> dpk, stats0
  {
    u64 w0  = wb0[ 0 * 256 + col], w1  = wb0[ 1 * 256 + col];
    u64 w2  = wb0[ 2 * 256 + col], w3  = wb0[ 3 * 256 + col];
    u64 w4  = wb0[ 4 * 256 + col], w5  = wb0[ 5 * 256 + col];
    u64 w6  = wb0[ 6 * 256 + col], w7  = wb0[ 7 * 256 + col];
    u64 w8  = wb0[ 8 * 256 + col], w9  = wb0[ 9 * 256 + col];
    u64 w10 = wb0[10 * 256 + col], w11 = wb0[11 * 256 + col];
    u64 w12 = wb0[12 * 256 + col];
    const float* base = x + (size_t)(row0 + wave * 8) * 784;  // 8 rows/wave
#pragma unroll 2
    for (int it = 0; it < 8; ++it) {
      u64 sel = pack784_sel(base + (size_t)it * 784, 0.5f, lane);
      if (lane < 13) aw[(wave * 8 + it) * 16 + lane] = sel;   // words 13..15 never read
    }
    __syncthreads();
    int sd = 0; unsigned sdd = 0;   // 32*784^2 = 19.7M fits u32
#pragma unroll
    for (int r = 0; r < 32; ++r) {
      const u64* ap = &aw[(h * 32 + r) * 16];
      int d = __popcll(ap[0] ^ w0)   + __popcll(ap[1] ^ w1)
            + __popcll(ap[2] ^ w2)   + __popcll(ap[3] ^ w3)
            + __popcll(ap[4] ^ w4)   + __popcll(ap[5] ^ w5)
            + __popcll(ap[6] ^ w6)   + __popcll(ap[7] ^ w7)
            + __popcll(ap[8] ^ w8)   + __popcll(ap[9] ^ w9)
            + __popcll(ap[10] ^ w10) + __popcll(ap[11] ^ w11)
            + __popcll(ap[12] ^ w12);
      DPK_SET(r, d);
      sd += d; sdd += (unsigned)(d * d);
    }
    if (h) { sdL[col] = (unsigned)sd; sddL[col] = sdd; }
    __syncthreads();
    if (!h)
      stats_add(&sumd[(rep * 5 + 0) * 256 + col],
                &sumdd[(rep * 5 + 0) * 256 + col],
                sd + (int)sdL[col], (u64)sdd + (u64)sddL[col]);
  }
  grid_barrier<512>(bar, 1, b);

  // ---- P2..P4: layers 1..3 — binarize dpk -> bits -> new dpk + next stats
#pragma unroll
  for (int k = 0; k < 3; ++k) {
    const float* gk  = (k == 0) ? g0  : (k == 1) ? g1  : g2;
    const float* bk  = (k == 0) ? bb0 : (k == 1) ? bb1 : bb2;
    const u64*   wbN = (k == 0) ? wb1 : (k == 1) ? wb2 : wb3;
    float gs, md;
    bn_gs_md(sumd, sumdd, k, col, gk, gs, md);
    const float A = -2.0f * gs;
    const float C = fmaf(gs, 2.0f * md, bk[col]);
#pragma unroll
    for (int r = 0; r < 32; ++r) {
      bool bit = fmaf(A, (float)DPK_GET(r), C) >= 0.0f;
      u64 m = __ballot(bit);
      if (lane == 0) bits[(hw * 32 + r) * 4 + cg] = m;
    }
    __syncthreads();
    u64 wn0 = wbN[0 * 256 + col], wn1 = wbN[1 * 256 + col];
    u64 wn2 = wbN[2 * 256 + col], wn3 = wbN[3 * 256 + col];
    int sd = 0; unsigned sdd = 0;   // 32 * 256^2 = 2.1M fits u32
#pragma unroll
    for (int r = 0; r < 32; ++r) {
      const u64* bp = &bits[(h * 32 + r) * 4];
      int d = __popcll(bp[0] ^ wn0) + __popcll(bp[1] ^ wn1)
            + __popcll(bp[2] ^ wn2) + __popcll(bp[3] ^ wn3);
      DPK_SET(r, d);
      sd += d; sdd += (unsigned)(d * d);
    }
    if (h) { sdL[col] = (unsigned)sd; sddL[col] = sdd; }
    __syncthreads();
    if (!h)
      stats_add(&sumd[(rep * 5 + k + 1) * 256 + col],
                &sumdd[(rep * 5 + k + 1) * 256 + col],
                sd + (int)sdL[col], (u64)sdd + (u64)sddL[col]);
    grid_barrier<512>(bar, 2 + k, b);
  }

  // ---- P5: layer 4 — binarize d3 -> bits -> d4 (10 cols) + stats4
  {
    float gs, md;
    bn_gs_md(sumd, sumdd, 3, col, g3, gs, md);
    const float A = -2.0f * gs;
    const float C = fmaf(gs, 2.0f * md, bb3[col]);
#pragma unroll
    for (int r = 0; r < 32; ++r) {
      bool bit = fmaf(A, (float)DPK_GET(r), C) >= 0.0f;
      u64 m = __ballot(bit);
      if (lane == 0) bits[(hw * 32 + r) * 4 + cg] = m;
    }
    __syncthreads();
    int sd = 0; unsigned sdd = 0;
    if (col < 10) {
      u64 wn0 = wb4[0 * 16 + col], wn1 = wb4[1 * 16 + col];
      u64 wn2 = wb4[2 * 16 + col], wn3 = wb4[3 * 16 + col];
#pragma unroll
      for (int r = 0; r < 32; ++r) {
        const u64* bp = &bits[(h * 32 + r) * 4];
        int d = __popcll(bp[0] ^ wn0) + __popcll(bp[1] ^ wn1)
              + __popcll(bp[2] ^ wn2) + __popcll(bp[3] ^ wn3);
        DPK_SET(r, d);
        sd += d; sdd += (unsigned)(d * d);
      }
      if (h) { sdL[col] = (unsigned)sd; sddL[col] = sdd; }
    }
    __syncthreads();
    if (!h && col < 10)
      stats_add(&sumd[(rep * 5 + 4) * 256 + col],
                &sumdd[(rep * 5 + 4) * 256 + col],
                sd + (int)sdL[col], (u64)sdd + (u64)sddL[col]);
  }
  grid_barrier<512>(bar, 5, b);

  // ---- P6: BN4 + softmax + store
  {
    if (col < 10) {
      float gs, md;
      bn_gs_md(sumd, sumdd, 4, col, g4, gs, md);
      const float A = -2.0f * gs;
      const float C = fmaf(gs, 2.0f * md, bb4[col]);
#pragma unroll
      for (int r = 0; r < 32; ++r)
        sY[(h * 32 + r) * 10 + col] = fmaf(A, (float)DPK_GET(r), C);
    }
    __syncthreads();
    if (tid < 64) {
      float y[10]; float mx = -1e30f;
#pragma unroll
      for (int c = 0; c < 10; ++c) { y[c] = sY[tid * 10 + c]; mx = fmaxf(mx, y[c]); }
      float sum = 0.0f;
#pragma unroll
      for (int c = 0; c < 10; ++c) { y[c] = __expf(y[c] - mx); sum += y[c]; }
      float inv = 1.0f / sum;
      float* op = out + (size_t)(row0 + tid) * 10;
#pragma unroll
      for (int c = 0; c < 10; ++c) op[c] = y[c] * inv;
    }
  }
}

// ================= fallback: proven r14/r16 kernel (512x64, 256 thr) ========
template<int NBLK, int RWS>
__global__ __launch_bounds__(256, 3) void fused_bnn(
    const float* __restrict__ x,
    const float* __restrict__ g0, const float* __restrict__ g1,
    const float* __restrict__ g2, const float* __restrict__ g3,
    const float* __restrict__ g4,
    const float* __restrict__ bb0, const float* __restrict__ bb1,
    const float* __restrict__ bb2, const float* __restrict__ bb3,
    const float* __restrict__ bb4,
    float* __restrict__ out, char* __restrict__ ws) {
  u64* wb0 = (u64*)(ws + OFF_WB0);
  u64* wb1 = (u64*)(ws + OFF_WB1);
  u64* wb2 = (u64*)(ws + OFF_WB2);
  u64* wb3 = (u64*)(ws + OFF_WB3);
  u64* wb4 = (u64*)(ws + OFF_WB4);
  int* sumd  = (int*)(ws + OFF_SUMD);
  u64* sumdd = (u64*)(ws + OFF_SUMDD);
  unsigned* bar = (unsigned*)(ws + OFF_BAR);

  const int b = blockIdx.x, tid = threadIdx.x;
  const int lane = tid & 63, wave = tid >> 6;
  const int row0 = b * RWS;
  const int rep = b & (NREP - 1);
  constexpr int RPW = RWS / 4;

  __shared__ u64 aw[RWS * 16];
  __shared__ u64 bits[RWS * 4];
  __shared__ float sY[RWS * 10];

  unsigned dpk[RWS / 2];

  {
    u64 w0  = wb0[ 0 * 256 + tid], w1  = wb0[ 1 * 256 + tid];
    u64 w2  = wb0[ 2 * 256 + tid], w3  = wb0[ 3 * 256 + tid];
    u64 w4  = wb0[ 4 * 256 + tid], w5  = wb0[ 5 * 256 + tid];
    u64 w6  = wb0[ 6 * 256 + tid], w7  = wb0[ 7 * 256 + tid];
    u64 w8  = wb0[ 8 * 256 + tid], w9  = wb0[ 9 * 256 + tid];
    u64 w10 = wb0[10 * 256 + tid], w11 = wb0[11 * 256 + tid];
    u64 w12 = wb0[12 * 256 + tid];
    const float* base = x + (size_t)(row0 + wave * RPW) * 784;
#pragma unroll 2
    for (int it = 0; it < RPW; ++it) {
      u64 sel = pack784_sel(base + (size_t)it * 784, 0.5f, lane);
      if (lane < 13) aw[(wave * RPW + it) * 16 + lane] = sel;
    }
    __syncthreads();
    int sd = 0; unsigned sdd = 0;
#pragma unroll
    for (int r = 0; r < RWS; ++r) {
      const u64* ap = &aw[r * 16];
      int d = __popcll(ap[0] ^ w0)   + __popcll(ap[1] ^ w1)
            + __popcll(ap[2] ^ w2)   + __popcll(ap[3] ^ w3)
            + __popcll(ap[4] ^ w4)   + __popcll(ap[5] ^ w5)
            + __popcll(ap[6] ^ w6)   + __popcll(ap[7] ^ w7)
            + __popcll(ap[8] ^ w8)   + __popcll(ap[9] ^ w9)
            + __popcll(ap[10] ^ w10) + __popcll(ap[11] ^ w11)
            + __popcll(ap[12] ^ w12);
      DPK_SET(r, d);
      sd += d; sdd += (unsigned)(d * d);
    }
    stats_add(&sumd[(rep * 5 + 0) * 256 + tid],
              &sumdd[(rep * 5 + 0) * 256 + tid], sd, (u64)sdd);
  }
  grid_barrier<NBLK>(bar, 1, b);

#pragma unroll
  for (int k = 0; k < 3; ++k) {
    const float* gk  = (k == 0) ? g0  : (k == 1) ? g1  : g2;
    const float* bk  = (k == 0) ? bb0 : (k == 1) ? bb1 : bb2;
    const u64*   wbN = (k == 0) ? wb1 : (k == 1) ? wb2 : wb3;
    float gs, md;
    bn_gs_md(sumd, sumdd, k, tid, gk, gs, md);
    const float A = -2.0f * gs;
    const float C = fmaf(gs, 2.0f * md, bk[tid]);
#pragma unroll
    for (int r = 0; r < RWS; ++r) {
      bool bit = fmaf(A, (float)DPK_GET(r), C) >= 0.0f;
      u64 m = __ballot(bit);
      if (lane == 0) bits[r * 4 + wave] = m;
    }
    __syncthreads();
    u64 wn0 = wbN[0 * 256 + tid], wn1 = wbN[1 * 256 + tid];
    u64 wn2 = wbN[2 * 256 + tid], wn3 = wbN[3 * 256 + tid];
    int sd = 0; unsigned sdd = 0;
#pragma unroll
    for (int r = 0; r < RWS; ++r) {
      int d = __popcll(bits[r*4+0] ^ wn0) + __popcll(bits[r*4+1] ^ wn1)
            + __popcll(bits[r*4+2] ^ wn2) + __popcll(bits[r*4+3] ^ wn3);
      DPK_SET(r, d);
      sd += d; sdd += (unsigned)(d * d);
    }
    stats_add(&sumd[(rep * 5 + k + 1) * 256 + tid],
              &sumdd[(rep * 5 + k + 1) * 256 + tid], sd, (u64)sdd);
    grid_barrier<NBLK>(bar, 2 + k, b);
  }

  {
    float gs, md;
    bn_gs_md(sumd, sumdd, 3, tid, g3, gs, md);
    const float A = -2.0f * gs;
    const float C = fmaf(gs, 2.0f * md, bb3[tid]);
#pragma unroll
    for (int r = 0; r < RWS; ++r) {
      bool bit = fmaf(A, (float)DPK_GET(r), C) >= 0.0f;
      u64 m = __ballot(bit);
      if (lane == 0) bits[r * 4 + wave] = m;
    }
    __syncthreads();
    if (tid < 10) {
      u64 wn0 = wb4[0 * 16 + tid], wn1 = wb4[1 * 16 + tid];
      u64 wn2 = wb4[2 * 16 + tid], wn3 = wb4[3 * 16 + tid];
      int sd = 0; unsigned sdd = 0;
#pragma unroll
      for (int r = 0; r < RWS; ++r) {
        int d = __popcll(bits[r*4+0] ^ wn0) + __popcll(bits[r*4+1] ^ wn1)
              + __popcll(bits[r*4+2] ^ wn2) + __popcll(bits[r*4+3] ^ wn3);
        DPK_SET(r, d);
        sd += d; sdd += (unsigned)(d * d);
      }
      stats_add(&sumd[(rep * 5 + 4) * 256 + tid],
                &sumdd[(rep * 5 + 4) * 256 + tid], sd, (u64)sdd);
    }
  }
  grid_barrier<NBLK>(bar, 5, b);

  {
    if (tid < 10) {
      float gs, md;
      bn_gs_md(sumd, sumdd, 4, tid, g4, gs, md);
      const float A = -2.0f * gs;
      const float C = fmaf(gs, 2.0f * md, bb4[tid]);
#pragma unroll
      for (int r = 0; r < RWS; ++r)
        sY[r * 10 + tid] = fmaf(A, (float)DPK_GET(r), C);
    }
    __syncthreads();
    if (tid < RWS) {
      float y[10]; float mx = -1e30f;
#pragma unroll
      for (int c = 0; c < 10; ++c) { y[c] = sY[tid * 10 + c]; mx = fmaxf(mx, y[c]); }
      float sum = 0.0f;
#pragma unroll
      for (int c = 0; c < 10; ++c) { y[c] = __expf(y[c] - mx); sum += y[c]; }
      float inv = 1.0f / sum;
      float* op = out + (size_t)(row0 + tid) * 10;
#pragma unroll
      for (int c = 0; c < 10; ++c) op[c] = y[c] * inv;
    }
  }
}

// ---------------- host ----------------
extern "C" void kernel_launch(void* const* d_in, const int* in_sizes, int n_in,
                              void* d_out, int out_size, void* d_ws, size_t ws_size,
                              hipStream_t stream) {
  (void)in_sizes; (void)n_in; (void)out_size; (void)ws_size;
  const float* x   = (const float*)d_in[0];
  const float* W0  = (const float*)d_in[1];
  const float* g0  = (const float*)d_in[2];
  const float* bb0 = (const float*)d_in[3];
  const float* W1  = (const float*)d_in[4];
  const float* g1  = (const float*)d_in[5];
  const float* bb1 = (const float*)d_in[6];
  const float* W2  = (const float*)d_in[7];
  const float* g2  = (const float*)d_in[8];
  const float* bb2 = (const float*)d_in[9];
  const float* W3  = (const float*)d_in[10];
  const float* g3  = (const float*)d_in[11];
  const float* bb3 = (const float*)d_in[12];
  const float* W4  = (const float*)d_in[13];
  const float* g4  = (const float*)d_in[14];
  const float* bb4 = (const float*)d_in[15];
  char* ws = (char*)d_ws;

  u64* wb0 = (u64*)(ws + OFF_WB0);
  u64* wb1 = (u64*)(ws + OFF_WB1);
  u64* wb2 = (u64*)(ws + OFF_WB2);
  u64* wb3 = (u64*)(ws + OFF_WB3);
  u64* wb4 = (u64*)(ws + OFF_WB4);

  pack_weights<<<257, 256, 0, stream>>>(W0, W1, W2, W3, W4,
                                        wb0, wb1, wb2, wb3, wb4,
                                        (int4*)(ws + OFF_SUMD));

  // Occupancy gate for the 512-thread variant: needs 2 blocks/CU co-resident;
  // require >=3 (verified margin; spin-barrier rule from r15's deadlock).
  static int cap512w = -1;
  if (cap512w < 0) {
    int nb = 0;
    if (hipOccupancyMaxActiveBlocksPerMultiprocessor(
            &nb, (const void*)fused_bnn2, 512, 0) != hipSuccess) nb = 0;
    (void)hipGetLastError();
    cap512w = nb;
  }

  if (cap512w >= 3) {
    fused_bnn2<<<512, 512, 0, stream>>>(
        x, g0, g1, g2, g3, g4, bb0, bb1, bb2, bb3, bb4,
        (float*)d_out, ws);
  } else {
    fused_bnn<512, 64><<<512, 256, 0, stream>>>(
        x, g0, g1, g2, g3, g4, bb0, bb1, bb2, bb3, bb4,
        (float*)d_out, ws);
  }
}

// Round 9
// 267.337 us; speedup vs baseline: 1.5493x; 1.0003x over previous
//
#include <hip/hip_runtime.h>
#include <stdint.h>

// Binarized 5-layer MLP, B=32768, dims 784->256->256->256->256->10.
// Round 19: 1024x32 with the LOOSE launch bound.
// Allocator behavior established r14/r16/r17/r18:
//   (256,3) 64-row -> 68 VGPR clean (capacity 7/CU);  (256,4) -> ~128 (cap 4);
//   (256,6) -> 40 + 6.3MB spill (slow);               (512,3) -> ~170 (cap 2).
// r17's occupancy experiment failed because the tightened bound wrecked
// codegen; with the PROVEN loose bound (256,3), 68 VGPR already gives
// capacity 7 >= gate 5, so <1024,32> can run at 4 blocks/CU (16 waves/CU)
// with r14-quality code. 32-row variant needs FEWER regs (dpk[16] vs [32]).
// Gate (host occupancy query, >=5 for a 4/CU need) + proven <512,64> fallback
// keep this deadlock-proof (spin-barrier rule from r15).
// Falsifiable fingerprints: pass -> LDS 6656, VGPR 55-70, WRITE ~7.6MB;
// fail -> LDS 12800 fallback at 131us.
// Barrier design unchanged (r14-verified, 433->131us): all cross-block data
// read-only (x, packed weights via kernel boundary) or MALL atomics; barrier =
// hierarchical relaxed arrivals (lines 256B apart) + relaxed poll on 16
// replicated gen lines; no cache maintenance ops.
// Math (verified r12-r18, absmax 0.00195): d = popcount(a XOR w);
// binarize(BN(h)) == (A*d + C >= 0), A = -2*g*s, C = 2*g*s*mean_d + b,
// s = rsqrt(4*(E[d^2]-E[d]^2)+eps). Stats = exact integer sums in 16
// replicated atomic slots; consumers reduce replicas.

typedef unsigned long long u64;

#define NREP 16

// ---- workspace layout (bytes) ----
#define OFF_WB0   0u          // u64 [16][256] = 32768 (words 0..12 used)
#define OFF_WB1   32768u      // u64 [4][256] = 8192
#define OFF_WB2   40960u
#define OFF_WB3   49152u
#define OFF_WB4   57344u      // u64 [4][16] = 512 (10 cols used)
#define OFF_SUMD  57856u      // int32 [16][5][256] = 81920
#define OFF_SUMDD 139776u     // u64   [16][5][256] = 163840
#define OFF_BAR   303616u     // 81 lines x 256B: <=64 group cnts, 1 root, 16 gen
#define ZERO_INT4 16656       // (81920+163840+81*256)/16, zeroed from OFF_SUMD

// 784-elem row -> 13 packed u64 words (consistent permuted bit order).
__device__ __forceinline__ u64 pack784_sel(const float* __restrict__ src,
                                           float thr, int lane) {
  u64 w[13];
  const float4* s4 = (const float4*)src;
#pragma unroll
  for (int j = 0; j < 3; ++j) {
    float4 v = s4[j * 64 + lane];
    w[4*j+0] = __ballot(v.x >= thr);
    w[4*j+1] = __ballot(v.y >= thr);
    w[4*j+2] = __ballot(v.z >= thr);
    w[4*j+3] = __ballot(v.w >= thr);
  }
  float4 v = make_float4(-1.f, -1.f, -1.f, -1.f);
  if (lane < 4) v = s4[192 + lane];
  u64 m0 = __ballot(v.x >= thr) & 0xFull;
  u64 m1 = __ballot(v.y >= thr) & 0xFull;
  u64 m2 = __ballot(v.z >= thr) & 0xFull;
  u64 m3 = __ballot(v.w >= thr) & 0xFull;
  w[12] = m0 | (m1 << 4) | (m2 << 8) | (m3 << 12);
  u64 sel = 0;
#pragma unroll
  for (int i = 0; i < 13; ++i) sel = (lane == i) ? w[i] : sel;
  return sel;
}

// 256-elem row -> 4 packed u64 words; bit l of word j <-> element 64*j+l.
__device__ __forceinline__ u64 pack256_sel(const float* __restrict__ src, int lane) {
  u64 w[4];
#pragma unroll
  for (int j = 0; j < 4; ++j) w[j] = __ballot(src[j * 64 + lane] >= 0.0f);
  u64 sel = 0;
#pragma unroll
  for (int i = 0; i < 4; ++i) sel = (lane == i) ? w[i] : sel;
  return sel;
}

// Reduce the 16 stats replicas for (layer, col) via MALL-fresh atomic loads.
__device__ __forceinline__ void bn_gs_md(const int* __restrict__ sumd_rep,
                                         const u64* __restrict__ sumdd_rep,
                                         int layer, int col,
                                         const float* __restrict__ g,
                                         float& gs, float& md_out) {
  long long sd = 0; u64 sdd = 0;
#pragma unroll
  for (int r = 0; r < NREP; ++r) {
    sd  += __hip_atomic_load(&sumd_rep [(r * 5 + layer) * 256 + col],
                             __ATOMIC_RELAXED, __HIP_MEMORY_SCOPE_AGENT);
    sdd += __hip_atomic_load(&sumdd_rep[(r * 5 + layer) * 256 + col],
                             __ATOMIC_RELAXED, __HIP_MEMORY_SCOPE_AGENT);
  }
  double md  = (double)sd  * (1.0 / 32768.0);
  double mdd = (double)sdd * (1.0 / 32768.0);
  float var = (float)(4.0 * (mdd - md * md));
  float s   = rsqrtf(var + 1e-5f);
  gs = g[col] * s;
  md_out = (float)md;
}

#define DPK_SET(r, d) do { if ((r) & 1) dpk[(r) >> 1] |= ((unsigned)(d)) << 16; \
                           else dpk[(r) >> 1] = (unsigned)(d); } while (0)
#define DPK_GET(r) ((int)((dpk[(r) >> 1] >> (((r) & 1) * 16)) & 0xFFFFu))

// Stats add: returning atomic form so vmcnt-retire == completed at the MALL.
__device__ __forceinline__ void stats_add(int* pd, u64* pdd, int sd, u64 sdd) {
  int o1 = atomicAdd(pd, sd);
  u64 o2 = atomicAdd(pdd, sdd);
  asm volatile("" :: "v"(o1), "v"(o2));
}

// ---- zero-cache-op hierarchical grid barrier (r14-verified) ----
// Monotonic counters; phase = 1..5. Lines 256B apart:
//   bar[g*64]            g<NGRP : group arrival counters
//   bar[NGRP*64]                : root counter
//   bar[(NGRP+1+r)*64]   r<16   : generation replicas
template<int NBLK>
__device__ __forceinline__ void grid_barrier(unsigned* bar, unsigned phase, int b) {
  constexpr unsigned NGRP = NBLK / 16;
  __syncthreads();
  if (threadIdx.x == 0) {
    asm volatile("s_waitcnt vmcnt(0)" ::: "memory");
    const unsigned g = (unsigned)b >> 4;           // b / 16
    unsigned a = __hip_atomic_fetch_add(&bar[g * 64], 1u, __ATOMIC_RELAXED,
                                        __HIP_MEMORY_SCOPE_AGENT) + 1u;
    bool released = false;
    if (a == phase * 16u) {                        // last of my group, this phase
      unsigned r = __hip_atomic_fetch_add(&bar[NGRP * 64], 1u, __ATOMIC_RELAXED,
                                          __HIP_MEMORY_SCOPE_AGENT) + 1u;
      if (r == phase * NGRP) {                     // last overall: release
#pragma unroll
        for (int i = 0; i < 16; ++i)
          __hip_atomic_store(&bar[(NGRP + 1 + i) * 64], phase, __ATOMIC_RELAXED,
                             __HIP_MEMORY_SCOPE_AGENT);
        released = true;
      }
    }
    if (!released) {
      const unsigned* genp = &bar[(NGRP + 1 + (b & 15)) * 64];
      while (__hip_atomic_load(genp, __ATOMIC_RELAXED,
                               __HIP_MEMORY_SCOPE_AGENT) < phase)
        __builtin_amdgcn_s_sleep(8);
    }
  }
  __syncthreads();
}

// ================= prep: pack weights + zero stats & barrier =================
__global__ __launch_bounds__(256) void pack_weights(
    const float* __restrict__ W0, const float* __restrict__ W1,
    const float* __restrict__ W2, const float* __restrict__ W3,
    const float* __restrict__ W4,
    u64* __restrict__ wb0, u64* __restrict__ wb1, u64* __restrict__ wb2,
    u64* __restrict__ wb3, u64* __restrict__ wb4, int4* __restrict__ zeroRgn) {
  const int b = blockIdx.x, tid = threadIdx.x;
  const int lane = tid & 63, wave = tid >> 6;
  int gid = b * 256 + tid;
  if (gid < ZERO_INT4) zeroRgn[gid] = make_int4(0, 0, 0, 0);
  if (b < 64) {
    int row = b * 4 + wave;
    u64 sel = pack784_sel(W0 + (size_t)row * 784, 0.0f, lane);
    if (lane < 13) wb0[lane * 256 + row] = sel;
  } else if (b < 128) {
    int row = (b - 64) * 4 + wave;
    u64 sel = pack256_sel(W1 + (size_t)row * 256, lane);
    if (lane < 4) wb1[lane * 256 + row] = sel;
  } else if (b < 192) {
    int row = (b - 128) * 4 + wave;
    u64 sel = pack256_sel(W2 + (size_t)row * 256, lane);
    if (lane < 4) wb2[lane * 256 + row] = sel;
  } else if (b < 256) {
    int row = (b - 192) * 4 + wave;
    u64 sel = pack256_sel(W3 + (size_t)row * 256, lane);
    if (lane < 4) wb3[lane * 256 + row] = sel;
  } else {
    for (int row = wave; row < 10; row += 4) {
      u64 sel = pack256_sel(W4 + (size_t)row * 256, lane);
      if (lane < 4) wb4[lane * 16 + row] = sel;
    }
  }
}

// ================= fused persistent kernel (regular launch) =================
// NBLK x RWS rows; NBLK*RWS == 32768. BOTH variants use the proven loose
// bound (256,3): the allocator gives ~68 VGPR clean code (r14), and 68 VGPR
// -> capacity 7 blocks/CU, enough for the 1024-variant's 4/CU need.
template<int NBLK, int RWS>
__global__ __launch_bounds__(256, 3) void fused_bnn(
    const float* __restrict__ x,
    const float* __restrict__ g0, const float* __restrict__ g1,
    const float* __restrict__ g2, const float* __restrict__ g3,
    const float* __restrict__ g4,
    const float* __restrict__ bb0, const float* __restrict__ bb1,
    const float* __restrict__ bb2, const float* __restrict__ bb3,
    const float* __restrict__ bb4,
    float* __restrict__ out, char* __restrict__ ws) {
  u64* wb0 = (u64*)(ws + OFF_WB0);
  u64* wb1 = (u64*)(ws + OFF_WB1);
  u64* wb2 = (u64*)(ws + OFF_WB2);
  u64* wb3 = (u64*)(ws + OFF_WB3);
  u64* wb4 = (u64*)(ws + OFF_WB4);
  int* sumd  = (int*)(ws + OFF_SUMD);
  u64* sumdd = (u64*)(ws + OFF_SUMDD);
  unsigned* bar = (unsigned*)(ws + OFF_BAR);

  const int b = blockIdx.x, tid = threadIdx.x;
  const int lane = tid & 63, wave = tid >> 6;
  const int row0 = b * RWS;           // this block owns rows row0..row0+RWS-1
  const int rep = b & (NREP - 1);
  constexpr int RPW = RWS / 4;        // rows packed per wave in P1

  __shared__ u64 aw[RWS * 16];        // layer-0 packed rows (13/16 words used)
  __shared__ u64 bits[RWS * 4];       // current activation bits
  __shared__ float sY[RWS * 10];      // layer-4 pre-softmax

  unsigned dpk[RWS / 2];              // RWS d-values, 2x16b packed, registers

  // ---- P1: layer 0 — pack RWS x-rows into LDS, d0 -> dpk, stats0
  {
    u64 w0  = wb0[ 0 * 256 + tid], w1  = wb0[ 1 * 256 + tid];
    u64 w2  = wb0[ 2 * 256 + tid], w3  = wb0[ 3 * 256 + tid];
    u64 w4  = wb0[ 4 * 256 + tid], w5  = wb0[ 5 * 256 + tid];
    u64 w6  = wb0[ 6 * 256 + tid], w7  = wb0[ 7 * 256 + tid];
    u64 w8  = wb0[ 8 * 256 + tid], w9  = wb0[ 9 * 256 + tid];
    u64 w10 = wb0[10 * 256 + tid], w11 = wb0[11 * 256 + tid];
    u64 w12 = wb0[12 * 256 + tid];
    const float* base = x + (size_t)(row0 + wave * RPW) * 784;
#pragma unroll 2
    for (int it = 0; it < RPW; ++it) {
      u64 sel = pack784_sel(base + (size_t)it * 784, 0.5f, lane);
      if (lane < 13) aw[(wave * RPW + it) * 16 + lane] = sel;  // words 13..15 never read
    }
    __syncthreads();
    int sd = 0; unsigned sdd = 0;   // RWS*784^2 <= 39.3M fits u32
#pragma unroll
    for (int r = 0; r < RWS; ++r) {
      const u64* ap = &aw[r * 16];
      int d = __popcll(ap[0] ^ w0)   + __popcll(ap[1] ^ w1)
            + __popcll(ap[2] ^ w2)   + __popcll(ap[3] ^ w3)
            + __popcll(ap[4] ^ w4)   + __popcll(ap[5] ^ w5)
            + __popcll(ap[6] ^ w6)   + __popcll(ap[7] ^ w7)
            + __popcll(ap[8] ^ w8)   + __popcll(ap[9] ^ w9)
            + __popcll(ap[10] ^ w10) + __popcll(ap[11] ^ w11)
            + __popcll(ap[12] ^ w12);
      DPK_SET(r, d);
      sd += d; sdd += (unsigned)(d * d);
    }
    stats_add(&sumd[(rep * 5 + 0) * 256 + tid],
              &sumdd[(rep * 5 + 0) * 256 + tid], sd, (u64)sdd);
  }
  grid_barrier<NBLK>(bar, 1, b);

  // ---- P2..P4: layers 1..3 — binarize dpk -> bits -> new dpk + next stats
#pragma unroll
  for (int k = 0; k < 3; ++k) {
    const float* gk  = (k == 0) ? g0  : (k == 1) ? g1  : g2;
    const float* bk  = (k == 0) ? bb0 : (k == 1) ? bb1 : bb2;
    const u64*   wbN = (k == 0) ? wb1 : (k == 1) ? wb2 : wb3;
    float gs, md;
    bn_gs_md(sumd, sumdd, k, tid, gk, gs, md);
    const float A = -2.0f * gs;
    const float C = fmaf(gs, 2.0f * md, bk[tid]);
#pragma unroll
    for (int r = 0; r < RWS; ++r) {
      bool bit = fmaf(A, (float)DPK_GET(r), C) >= 0.0f;
      u64 m = __ballot(bit);
      if (lane == 0) bits[r * 4 + wave] = m;
    }
    __syncthreads();
    u64 wn0 = wbN[0 * 256 + tid], wn1 = wbN[1 * 256 + tid];
    u64 wn2 = wbN[2 * 256 + tid], wn3 = wbN[3 * 256 + tid];
    int sd = 0; unsigned sdd = 0;   // RWS * 256^2 <= 4.2M fits u32
#pragma unroll
    for (int r = 0; r < RWS; ++r) {
      int d = __popcll(bits[r*4+0] ^ wn0) + __popcll(bits[r*4+1] ^ wn1)
            + __popcll(bits[r*4+2] ^ wn2) + __popcll(bits[r*4+3] ^ wn3);
      DPK_SET(r, d);
      sd += d; sdd += (unsigned)(d * d);
    }
    stats_add(&sumd[(rep * 5 + k + 1) * 256 + tid],
              &sumdd[(rep * 5 + k + 1) * 256 + tid], sd, (u64)sdd);
    grid_barrier<NBLK>(bar, 2 + k, b);
  }

  // ---- P5: layer 4 — binarize d3 -> bits -> d4 (10 cols, in dpk of tid<10)
  {
    float gs, md;
    bn_gs_md(sumd, sumdd, 3, tid, g3, gs, md);
    const float A = -2.0f * gs;
    const float C = fmaf(gs, 2.0f * md, bb3[tid]);
#pragma unroll
    for (int r = 0; r < RWS; ++r) {
      bool bit = fmaf(A, (float)DPK_GET(r), C) >= 0.0f;
      u64 m = __ballot(bit);
      if (lane == 0) bits[r * 4 + wave] = m;
    }
    __syncthreads();
    if (tid < 10) {
      u64 wn0 = wb4[0 * 16 + tid], wn1 = wb4[1 * 16 + tid];
      u64 wn2 = wb4[2 * 16 + tid], wn3 = wb4[3 * 16 + tid];
      int sd = 0; unsigned sdd = 0;
#pragma unroll
      for (int r = 0; r < RWS; ++r) {
        int d = __popcll(bits[r*4+0] ^ wn0) + __popcll(bits[r*4+1] ^ wn1)
              + __popcll(bits[r*4+2] ^ wn2) + __popcll(bits[r*4+3] ^ wn3);
        DPK_SET(r, d);
        sd += d; sdd += (unsigned)(d * d);
      }
      stats_add(&sumd[(rep * 5 + 4) * 256 + tid],
                &sumdd[(rep * 5 + 4) * 256 + tid], sd, (u64)sdd);
    }
  }
  grid_barrier<NBLK>(bar, 5, b);

  // ---- P6: BN4 + softmax + store
  {
    if (tid < 10) {
      float gs, md;
      bn_gs_md(sumd, sumdd, 4, tid, g4, gs, md);
      const float A = -2.0f * gs;
      const float C = fmaf(gs, 2.0f * md, bb4[tid]);
#pragma unroll
      for (int r = 0; r < RWS; ++r)
        sY[r * 10 + tid] = fmaf(A, (float)DPK_GET(r), C);
    }
    __syncthreads();
    if (tid < RWS) {
      float y[10]; float mx = -1e30f;
#pragma unroll
      for (int c = 0; c < 10; ++c) { y[c] = sY[tid * 10 + c]; mx = fmaxf(mx, y[c]); }
      float sum = 0.0f;
#pragma unroll
      for (int c = 0; c < 10; ++c) { y[c] = __expf(y[c] - mx); sum += y[c]; }
      float inv = 1.0f / sum;
      float* op = out + (size_t)(row0 + tid) * 10;
#pragma unroll
      for (int c = 0; c < 10; ++c) op[c] = y[c] * inv;
    }
  }
}

// ---------------- host ----------------
extern "C" void kernel_launch(void* const* d_in, const int* in_sizes, int n_in,
                              void* d_out, int out_size, void* d_ws, size_t ws_size,
                              hipStream_t stream) {
  (void)in_sizes; (void)n_in; (void)out_size; (void)ws_size;
  const float* x   = (const float*)d_in[0];
  const float* W0  = (const float*)d_in[1];
  const float* g0  = (const float*)d_in[2];
  const float* bb0 = (const float*)d_in[3];
  const float* W1  = (const float*)d_in[4];
  const float* g1  = (const float*)d_in[5];
  const float* bb1 = (const float*)d_in[6];
  const float* W2  = (const float*)d_in[7];
  const float* g2  = (const float*)d_in[8];
  const float* bb2 = (const float*)d_in[9];
  const float* W3  = (const float*)d_in[10];
  const float* g3  = (const float*)d_in[11];
  const float* bb3 = (const float*)d_in[12];
  const float* W4  = (const float*)d_in[13];
  const float* g4  = (const float*)d_in[14];
  const float* bb4 = (const float*)d_in[15];
  char* ws = (char*)d_ws;

  u64* wb0 = (u64*)(ws + OFF_WB0);
  u64* wb1 = (u64*)(ws + OFF_WB1);
  u64* wb2 = (u64*)(ws + OFF_WB2);
  u64* wb3 = (u64*)(ws + OFF_WB3);
  u64* wb4 = (u64*)(ws + OFF_WB4);

  pack_weights<<<257, 256, 0, stream>>>(W0, W1, W2, W3, W4,
                                        wb0, wb1, wb2, wb3, wb4,
                                        (int4*)(ws + OFF_SUMD));

  // Occupancy gate (spin-barrier rule from r15's deadlock): the 1024-block
  // variant needs 4 blocks/CU co-resident; require VERIFIED capacity >=5.
  static int cap1024 = -1;
  if (cap1024 < 0) {
    int nb = 0;
    if (hipOccupancyMaxActiveBlocksPerMultiprocessor(
            &nb, (const void*)fused_bnn<1024, 32>, 256, 0) != hipSuccess) nb = 0;
    (void)hipGetLastError();
    cap1024 = nb;
  }

  if (cap1024 >= 5) {
    fused_bnn<1024, 32><<<1024, 256, 0, stream>>>(
        x, g0, g1, g2, g3, g4, bb0, bb1, bb2, bb3, bb4,
        (float*)d_out, ws);
  } else {
    fused_bnn<512, 64><<<512, 256, 0, stream>>>(
        x, g0, g1, g2, g3, g4, bb0, bb1, bb2, bb3, bb4,
        (float*)d_out, ws);
  }
}